// Round 17
// baseline (93.756 us; speedup 1.0000x reference)
//
#include <hip/hip_runtime.h>

#define NODES 4096
#define NDIM  512
#define HID   4096

typedef __attribute__((ext_vector_type(8))) short bf16x8;
typedef __attribute__((ext_vector_type(4))) float f32x4;

__device__ __forceinline__ float b2f(short v) {
  union { unsigned int u; float f; } c;
  c.u = ((unsigned int)(unsigned short)v) << 16;
  return c.f;
}
__device__ __forceinline__ short f2b(float f) {
  union { float f; unsigned int u; } c; c.f = f;
  unsigned int r = c.u + 0x7fffu + ((c.u >> 16) & 1u);  // round-nearest-even
  return (short)(r >> 16);
}

// ---- K0: fused prep: cast x->bf16 (16B stores) | transpose W1 | init accs ----
__global__ __launch_bounds__(256) void k_prep(const float* __restrict__ x,
                                              const float* __restrict__ W1,
                                              const float* __restrict__ b2,
                                              const float* __restrict__ b4,
                                              short* __restrict__ xb,
                                              short* __restrict__ w1t,
                                              float* __restrict__ aacc,
                                              float* __restrict__ svec,
                                              float* __restrict__ out) {
  __shared__ float tile[32][33];
  int b = blockIdx.x;
  if (b < 1024) {                       // cast x (4096x512 fp32 -> bf16), 8/thread
    int i = (b * 256 + threadIdx.x) * 8;
    float4 v0 = *(const float4*)(x + i);
    float4 v1 = *(const float4*)(x + i + 4);
    bf16x8 o;
    o[0] = f2b(v0.x); o[1] = f2b(v0.y); o[2] = f2b(v0.z); o[3] = f2b(v0.w);
    o[4] = f2b(v1.x); o[5] = f2b(v1.y); o[6] = f2b(v1.z); o[7] = f2b(v1.w);
    *(bf16x8*)(xb + i) = o;
  } else if (b < 3072) {                // transpose W1 [512][4096] -> [4096][512] bf16
    int t = b - 1024;
    int n0 = (t & 127) * 32;
    int k0 = (t >> 7) * 32;
    int tx = threadIdx.x & 31, ty = threadIdx.x >> 5;
    #pragma unroll
    for (int j = 0; j < 4; ++j) {
      int kk = ty + j * 8;
      tile[kk][tx] = W1[(size_t)(k0 + kk) * HID + n0 + tx];
    }
    __syncthreads();
    #pragma unroll
    for (int j = 0; j < 4; ++j) {
      int nn = ty + j * 8;
      w1t[(size_t)(n0 + nn) * NDIM + k0 + tx] = f2b(tile[tx][nn]);
    }
  } else {                              // init: a=0, s=N*b2, out=b4
    int j = (b - 3072) * 256 + threadIdx.x;
    aacc[j] = 0.0f;
    svec[j] = (float)NODES * b2[j];
    if (b == 3072 && threadIdx.x == 0) out[0] = b4[0];
  }
}

// ---- K1: A = relu(x @ W1 + b1) (bf16 MFMA), fused column sums ----
// 256x256 tile, BK=64, 8 waves (2M x 4N, 128x64/wave). 4-phase fine-interleave
// per K-tile: {ds_read || half-tile stage -> barrier -> lgkmcnt(0) -> 16 MFMA
// -> barrier}, counted vmcnt(8). Granule swizzle + padded-LDS repack epilogue.
__global__ __launch_bounds__(512, 2) void k_gemm1(const short* __restrict__ xb,
                                                  const short* __restrict__ w1t,
                                                  const float* __restrict__ b1,
                                                  short* __restrict__ Aout,
                                                  float* __restrict__ colsum) {
  extern __shared__ char smem[];        // 131072 B:
                                        // A: buf*32768 + kh*16384   (0..65535)
                                        // B: 65536 + buf*32768 + kh*16384
  __shared__ float csum[256];

  const int tid  = threadIdx.x;
  const int lane = tid & 63;
  const int wid  = tid >> 6;            // 0..7
  const int wr   = wid >> 2;            // 0..1  (M)
  const int wc   = wid & 3;             // 0..3  (N)

  // XCD-aware swizzle (256 blocks, %8==0 -> simple bijective form)
  int bswz = (blockIdx.x & 7) * 32 + (blockIdx.x >> 3);
  const int brow = (bswz >> 4) * 256, bcol = (bswz & 15) * 256;

  f32x4 acc[8][4];
  #pragma unroll
  for (int i = 0; i < 8; ++i)
    #pragma unroll
    for (int j = 0; j < 4; ++j)
      acc[i][j] = (f32x4){0.f, 0.f, 0.f, 0.f};

  if (tid < 256) csum[tid] = 0.f;

  const int fr = lane & 15;
  // swizzled fragment granule: logical g = lane>>4, row-phase = (fr>>1)&3
  const int fko = ((lane >> 4) ^ ((lane >> 1) & 3)) * 8;  // shorts, in [0,32)

  // staging: each kh-subtile is [256][32] shorts (64-B rows), LDS dest linear.
  // Source granule pre-swizzled with the SAME involution: g' = g ^ ((row>>1)&3).
  const int off0 = tid * 16;
  const int row0 = off0 >> 6;
  const int gs   = (off0 >> 4) & 3;                     // linear granule
  const int ce0  = (gs ^ ((row0 >> 1) & 3)) * 8;        // swizzled source offset
  const short* gA0 = xb  + (size_t)(brow + row0) * NDIM + ce0;
  const short* gA1 = xb  + (size_t)(brow + row0 + 128) * NDIM + ce0;
  const short* gB0 = w1t + (size_t)(bcol + row0) * NDIM + ce0;
  const short* gB1 = w1t + (size_t)(bcol + row0 + 128) * NDIM + ce0;

#define GLOAD(src, dst) __builtin_amdgcn_global_load_lds( \
    (const __attribute__((address_space(1))) void*)(src), \
    (__attribute__((address_space(3))) void*)(dst), 16, 0, 0)

#define STAGE_HALF(buf, tile_, kh) do { \
    char* bA_ = smem + (buf) * 32768 + (kh) * 16384; \
    char* bB_ = smem + 65536 + (buf) * 32768 + (kh) * 16384; \
    int ks_ = (tile_) * 64 + (kh) * 32; \
    GLOAD(gA0 + ks_, bA_ + off0); \
    GLOAD(gA1 + ks_, bA_ + off0 + 8192); \
    GLOAD(gB0 + ks_, bB_ + off0); \
    GLOAD(gB1 + ks_, bB_ + off0 + 8192); \
  } while (0)

#define DS_BFR(buf, kh) do { \
    const short* Bb_ = (const short*)(smem + 65536 + (buf) * 32768 + (kh) * 16384); \
    _Pragma("unroll") \
    for (int ni = 0; ni < 4; ++ni) \
      bfr[ni] = *(const bf16x8*)(Bb_ + (wc * 64 + ni * 16 + fr) * 32 + fko); \
  } while (0)

#define DS_AF(buf, kh, mh) do { \
    const short* Ab_ = (const short*)(smem + (buf) * 32768 + (kh) * 16384); \
    _Pragma("unroll") \
    for (int mi = 0; mi < 4; ++mi) \
      af[mi] = *(const bf16x8*)(Ab_ + (wr * 128 + ((mh) * 4 + mi) * 16 + fr) * 32 + fko); \
  } while (0)

  // swapped operands: acc[mi][ni] = C^T fragment
  // value(lane,reg) = C[row = mi*16+(lane&15)][col = ni*16+(lane>>4)*4+reg]
#define MFMA16(mh) do { \
    __builtin_amdgcn_s_setprio(1); \
    _Pragma("unroll") \
    for (int mi = 0; mi < 4; ++mi) \
      _Pragma("unroll") \
      for (int ni = 0; ni < 4; ++ni) \
        acc[(mh) * 4 + mi][ni] = __builtin_amdgcn_mfma_f32_16x16x32_bf16( \
            bfr[ni], af[mi], acc[(mh) * 4 + mi][ni], 0, 0, 0); \
    __builtin_amdgcn_s_setprio(0); \
  } while (0)

#define BAR() __builtin_amdgcn_s_barrier()
#define LGKM0() asm volatile("s_waitcnt lgkmcnt(0)" ::: "memory")
#define WCNT(s) asm volatile("s_waitcnt " s ::: "memory")

#define ITER(kk, DO_S0, DO_S2, V1, V3) do { \
    int b_ = (kk) & 1; \
    bf16x8 af[4], bfr[4]; \
    if (DO_S0) STAGE_HALF(((kk) + 1) & 1, (kk) + 1, 1); \
    DS_BFR(b_, 0); DS_AF(b_, 0, 0); \
    BAR(); LGKM0(); \
    MFMA16(0); \
    BAR(); \
    DS_AF(b_, 0, 1); \
    BAR(); LGKM0(); \
    MFMA16(1); \
    WCNT(V1); BAR(); \
    if (DO_S2) STAGE_HALF(b_, (kk) + 2, 0); \
    DS_BFR(b_, 1); DS_AF(b_, 1, 0); \
    BAR(); LGKM0(); \
    MFMA16(0); \
    BAR(); \
    DS_AF(b_, 1, 1); \
    BAR(); LGKM0(); \
    MFMA16(1); \
    WCNT(V3); BAR(); \
  } while (0)

  // prologue: kh0(0), kh1(0), kh0(1) in flight (12); retire kh0(0)
  STAGE_HALF(0, 0, 0);
  STAGE_HALF(0, 0, 1);
  STAGE_HALF(1, 1, 0);
  WCNT("vmcnt(8)");
  BAR();

  #pragma unroll 1
  for (int kt = 0; kt < 6; ++kt)
    ITER(kt, true, true, "vmcnt(8)", "vmcnt(8)");
  ITER(6, true, false, "vmcnt(8)", "vmcnt(4)");
  ITER(7, false, false, "vmcnt(0)", "vmcnt(0)");

  // ---- epilogue: bias + relu + csum; padded-LDS repack -> coalesced stores
  const int cr = lane & 15;            // output row within 16-frag
  const int cg = (lane >> 4) * 4;      // output col base within 16-frag
  float4 bias4[4];
  #pragma unroll
  for (int ni = 0; ni < 4; ++ni)
    bias4[ni] = *(const float4*)(b1 + bcol + wc * 64 + ni * 16 + cg);

  float cl[4][4];
  #pragma unroll
  for (int ni = 0; ni < 4; ++ni)
    #pragma unroll
    for (int r = 0; r < 4; ++r)
      cl[ni][r] = 0.f;

  short* pk = (short*)smem;            // [128][264] shorts = 67584 B (fits 128 KB)
  #pragma unroll 1
  for (int half = 0; half < 2; ++half) {
    __syncthreads();                   // K-loop reads / prev half's stores done
    if (wr == half) {                  // owning waves write their 128 rows
      #pragma unroll
      for (int mi = 0; mi < 8; ++mi) {
        int lrow = mi * 16 + cr;       // 0..127 within half
        #pragma unroll
        for (int ni = 0; ni < 4; ++ni) {
          float v0 = fmaxf(acc[mi][ni][0] + bias4[ni].x, 0.f);
          float v1 = fmaxf(acc[mi][ni][1] + bias4[ni].y, 0.f);
          float v2 = fmaxf(acc[mi][ni][2] + bias4[ni].z, 0.f);
          float v3 = fmaxf(acc[mi][ni][3] + bias4[ni].w, 0.f);
          cl[ni][0] += v0; cl[ni][1] += v1; cl[ni][2] += v2; cl[ni][3] += v3;
          short4 o;
          o.x = f2b(v0); o.y = f2b(v1); o.z = f2b(v2); o.w = f2b(v3);
          *(short4*)(pk + lrow * 264 + wc * 64 + ni * 16 + cg) = o;
        }
      }
    }
    __syncthreads();
    // all 8 waves store 64 KB: 128 rows x 512 B, fully coalesced b128
    #pragma unroll
    for (int i = 0; i < 8; ++i) {
      int c = tid + i * 512;           // 0..4095 chunks of 16 B
      int row = c >> 5, ch = c & 31;
      bf16x8 vv = *(const bf16x8*)(pk + row * 264 + ch * 8);
      *(bf16x8*)(Aout + (size_t)(brow + half * 128 + row) * HID + bcol + ch * 8) = vv;
    }
  }

  // column sums: reduce over the 16 rows (lanes sharing lane>>4)
  #pragma unroll
  for (int ni = 0; ni < 4; ++ni)
    #pragma unroll
    for (int r = 0; r < 4; ++r) {
      #pragma unroll
      for (int m = 1; m < 16; m <<= 1)
        cl[ni][r] += __shfl_xor(cl[ni][r], m);
    }
  if (cr == 0) {                       // 4 lanes/wave; wr=0/1 -> 2-way contention
    #pragma unroll
    for (int ni = 0; ni < 4; ++ni)
      #pragma unroll
      for (int r = 0; r < 4; ++r)
        atomicAdd(&csum[wc * 64 + ni * 16 + cg + r], cl[ni][r]);
  }
  __syncthreads();
  if (tid < 256) atomicAdd(&colsum[bcol + tid], csum[tid]);
}

// ---- K2: vout[col] += sum_i vin[i] * W[i][col]  (W: [4096][4096] fp32) ----
__global__ __launch_bounds__(256) void k_gemv_at(const float* __restrict__ W,
                                                 const float* __restrict__ vin,
                                                 float* __restrict__ vout) {
  const int col = blockIdx.x * 1024 + threadIdx.x * 4;
  const int r0  = blockIdx.y * 64;
  float4 accv = {0.f, 0.f, 0.f, 0.f};
  const float* base = W + (size_t)r0 * HID + col;
  #pragma unroll 16
  for (int i = 0; i < 64; ++i) {
    float vi = vin[r0 + i];
    float4 wv = *(const float4*)(base + (size_t)i * HID);
    accv.x += vi * wv.x; accv.y += vi * wv.y;
    accv.z += vi * wv.z; accv.w += vi * wv.w;
  }
  atomicAdd(&vout[col + 0], accv.x);
  atomicAdd(&vout[col + 1], accv.y);
  atomicAdd(&vout[col + 2], accv.z);
  atomicAdd(&vout[col + 3], accv.w);
}

// ---- K3: t[row] = W2[row,:] . s ; extra block computes beta = b2 . s ----
__global__ __launch_bounds__(256) void k_gemv_row(const float* __restrict__ W,
                                                  const float* __restrict__ vin,
                                                  const float* __restrict__ b2,
                                                  float* __restrict__ vout,
                                                  float* __restrict__ beta) {
  __shared__ float red[4];
  if (blockIdx.x == HID / 4) {           // beta block
    float p = 0.f;
    for (int j = threadIdx.x; j < HID; j += 256) p += b2[j] * vin[j];
    #pragma unroll
    for (int o = 32; o > 0; o >>= 1) p += __shfl_down(p, o);
    int lane = threadIdx.x & 63, w = threadIdx.x >> 6;
    if (lane == 0) red[w] = p;
    __syncthreads();
    if (threadIdx.x == 0) beta[0] = red[0] + red[1] + red[2] + red[3];
    return;
  }
  int w = threadIdx.x >> 6, lane = threadIdx.x & 63;
  int row = blockIdx.x * 4 + w;
  const float* base = W + (size_t)row * HID;
  float p = 0.f;
  #pragma unroll 8
  for (int j = lane * 4; j < HID; j += 256) {
    float4 wv = *(const float4*)(base + j);
    float4 sv = *(const float4*)(vin + j);
    p += wv.x * sv.x + wv.y * sv.y + wv.z * sv.z + wv.w * sv.w;
  }
  #pragma unroll
  for (int o = 32; o > 0; o >>= 1) p += __shfl_down(p, o);
  if (lane == 0) vout[row] = p;
}

// ---- K4: kv[row] = A[row,:] . t + beta   (A bf16) ----
__global__ __launch_bounds__(256) void k_kv(const short* __restrict__ A,
                                            const float* __restrict__ t,
                                            const float* __restrict__ beta,
                                            float* __restrict__ kv) {
  int w = threadIdx.x >> 6, lane = threadIdx.x & 63;
  int row = blockIdx.x * 4 + w;
  const short* base = A + (size_t)row * HID;
  float p = 0.f;
  #pragma unroll
  for (int j = lane * 8; j < HID; j += 512) {
    bf16x8 av = *(const bf16x8*)(base + j);
    float4 t0 = *(const float4*)(t + j);
    float4 t1 = *(const float4*)(t + j + 4);
    p += b2f(av[0]) * t0.x + b2f(av[1]) * t0.y + b2f(av[2]) * t0.z + b2f(av[3]) * t0.w
       + b2f(av[4]) * t1.x + b2f(av[5]) * t1.y + b2f(av[6]) * t1.z + b2f(av[7]) * t1.w;
  }
  #pragma unroll
  for (int o = 32; o > 0; o >>= 1) p += __shfl_down(p, o);
  if (lane == 0) kv[row] = p + beta[0];
}

// ---- K5: fused W3 pass + final: out += sum_c relu(b3[c] + sum_r kv[r]W3[r][c]) W4[c]
// 256 blocks x 512 threads; block owns 16 complete columns (32 row-groups x 128).
__global__ __launch_bounds__(512) void k_w3_final(const float* __restrict__ W3,
                                                  const float* __restrict__ kvv,
                                                  const float* __restrict__ b3,
                                                  const float* __restrict__ W4,
                                                  float* __restrict__ out) {
  __shared__ float part[512];
  const int t  = threadIdx.x;
  const int cl = t & 15;                 // col within block
  const int rg = t >> 4;                 // row-group 0..31
  const int c  = blockIdx.x * 16 + cl;
  const float* base = W3 + (size_t)rg * 128 * HID + c;
  const float* kb   = kvv + rg * 128;
  float p = 0.f;
  #pragma unroll 32
  for (int i = 0; i < 128; ++i)
    p += kb[i] * base[(size_t)i * HID];
  part[t] = p;
  __syncthreads();
  if (t < 16) {
    float u = b3[c];
    #pragma unroll
    for (int g = 0; g < 32; ++g) u += part[g * 16 + t];
    u = fmaxf(u, 0.f);
    float v = u * W4[c];
    #pragma unroll
    for (int o = 8; o > 0; o >>= 1) v += __shfl_down(v, o);
    if (t == 0) atomicAdd(out, v);
  }
}

extern "C" void kernel_launch(void* const* d_in, const int* in_sizes, int n_in,
                              void* d_out, int out_size, void* d_ws, size_t ws_size,
                              hipStream_t stream) {
  const float* x  = (const float*)d_in[0];
  // d_in[1] = edge_index (dead in the reference)
  const float* W1 = (const float*)d_in[2];
  const float* b1 = (const float*)d_in[3];
  const float* W2 = (const float*)d_in[4];
  const float* b2 = (const float*)d_in[5];
  const float* W3 = (const float*)d_in[6];
  const float* b3 = (const float*)d_in[7];
  const float* W4 = (const float*)d_in[8];
  const float* b4 = (const float*)d_in[9];
  float* out = (float*)d_out;

  char* ws = (char*)d_ws;
  short* Abf  = (short*)(ws);                 // 32 MB
  short* xb   = (short*)(ws + 33554432);      // 4 MB
  short* w1t  = (short*)(ws + 37748736);      // 4 MB
  float* aacc = (float*)(ws + 41943040);
  float* svec = (float*)(ws + 41959424);
  float* tvec = (float*)(ws + 41975808);
  float* kvv  = (float*)(ws + 41992192);
  float* beta = (float*)(ws + 42024960);

  k_prep    <<<dim3(3088),     dim3(256), 0, stream>>>(x, W1, b2, b4, xb, w1t, aacc, svec, out);
  k_gemm1   <<<dim3(256),      dim3(512), 131072, stream>>>(xb, w1t, b1, Abf, aacc);
  k_gemv_at <<<dim3(4, 64),    dim3(256), 0, stream>>>(W2, aacc, svec);
  k_gemv_row<<<dim3(1025),     dim3(256), 0, stream>>>(W2, svec, b2, tvec, beta);
  k_kv      <<<dim3(1024),     dim3(256), 0, stream>>>(Abf, tvec, beta, kvv);
  k_w3_final<<<dim3(256),      dim3(512), 0, stream>>>(W3, kvv, b3, W4, out);
}

// Round 18
// 86.417 us; speedup vs baseline: 1.0849x; 1.0849x over previous
//
#include <hip/hip_runtime.h>

#define NODES 4096
#define NDIM  512
#define HID   4096

typedef __attribute__((ext_vector_type(8))) short bf16x8;
typedef __attribute__((ext_vector_type(4))) float f32x4;

__device__ __forceinline__ float b2f(short v) {
  union { unsigned int u; float f; } c;
  c.u = ((unsigned int)(unsigned short)v) << 16;
  return c.f;
}
__device__ __forceinline__ short f2b(float f) {
  union { float f; unsigned int u; } c; c.f = f;
  unsigned int r = c.u + 0x7fffu + ((c.u >> 16) & 1u);  // round-nearest-even
  return (short)(r >> 16);
}

// ---- K0: fused prep: cast x->bf16 (16B stores) | transpose W1 | init accs ----
__global__ __launch_bounds__(256) void k_prep(const float* __restrict__ x,
                                              const float* __restrict__ W1,
                                              const float* __restrict__ b2,
                                              const float* __restrict__ b4,
                                              short* __restrict__ xb,
                                              short* __restrict__ w1t,
                                              float* __restrict__ aacc,
                                              float* __restrict__ svec,
                                              float* __restrict__ out) {
  __shared__ float tile[32][33];
  int b = blockIdx.x;
  if (b < 1024) {                       // cast x (4096x512 fp32 -> bf16), 8/thread
    int i = (b * 256 + threadIdx.x) * 8;
    float4 v0 = *(const float4*)(x + i);
    float4 v1 = *(const float4*)(x + i + 4);
    bf16x8 o;
    o[0] = f2b(v0.x); o[1] = f2b(v0.y); o[2] = f2b(v0.z); o[3] = f2b(v0.w);
    o[4] = f2b(v1.x); o[5] = f2b(v1.y); o[6] = f2b(v1.z); o[7] = f2b(v1.w);
    *(bf16x8*)(xb + i) = o;
  } else if (b < 3072) {                // transpose W1 [512][4096] -> [4096][512] bf16
    int t = b - 1024;
    int n0 = (t & 127) * 32;
    int k0 = (t >> 7) * 32;
    int tx = threadIdx.x & 31, ty = threadIdx.x >> 5;
    #pragma unroll
    for (int j = 0; j < 4; ++j) {
      int kk = ty + j * 8;
      tile[kk][tx] = W1[(size_t)(k0 + kk) * HID + n0 + tx];
    }
    __syncthreads();
    #pragma unroll
    for (int j = 0; j < 4; ++j) {
      int nn = ty + j * 8;
      w1t[(size_t)(n0 + nn) * NDIM + k0 + tx] = f2b(tile[tx][nn]);
    }
  } else {                              // init: a=0, s=N*b2, out=b4
    int j = (b - 3072) * 256 + threadIdx.x;
    aacc[j] = 0.0f;
    svec[j] = (float)NODES * b2[j];
    if (b == 3072 && threadIdx.x == 0) out[0] = b4[0];
  }
}

// ---- K1: A = relu(x @ W1 + b1) (bf16 MFMA), fused column sums ----
// 256x256 tile, BK=64, 8 waves (2M x 4N, 128x64/wave). 4-phase fine-interleave
// per K-tile: {ds_read || half-tile stage -> barrier -> lgkmcnt(0) -> 16 MFMA
// -> barrier}, counted vmcnt(8). Granule swizzle + padded-LDS repack epilogue.
__global__ __launch_bounds__(512, 2) void k_gemm1(const short* __restrict__ xb,
                                                  const short* __restrict__ w1t,
                                                  const float* __restrict__ b1,
                                                  short* __restrict__ Aout,
                                                  float* __restrict__ colsum) {
  extern __shared__ char smem[];        // 131072 B:
                                        // A: buf*32768 + kh*16384   (0..65535)
                                        // B: 65536 + buf*32768 + kh*16384
  __shared__ float csum[256];

  const int tid  = threadIdx.x;
  const int lane = tid & 63;
  const int wid  = tid >> 6;            // 0..7
  const int wr   = wid >> 2;            // 0..1  (M)
  const int wc   = wid & 3;             // 0..3  (N)

  // XCD-aware swizzle (256 blocks, %8==0 -> simple bijective form)
  int bswz = (blockIdx.x & 7) * 32 + (blockIdx.x >> 3);
  const int brow = (bswz >> 4) * 256, bcol = (bswz & 15) * 256;

  f32x4 acc[8][4];
  #pragma unroll
  for (int i = 0; i < 8; ++i)
    #pragma unroll
    for (int j = 0; j < 4; ++j)
      acc[i][j] = (f32x4){0.f, 0.f, 0.f, 0.f};

  if (tid < 256) csum[tid] = 0.f;

  const int fr = lane & 15;
  // swizzled fragment granule: logical g = lane>>4, row-phase = (fr>>1)&3
  const int fko = ((lane >> 4) ^ ((lane >> 1) & 3)) * 8;  // shorts, in [0,32)

  // staging: each kh-subtile is [256][32] shorts (64-B rows), LDS dest linear.
  // Source granule pre-swizzled with the SAME involution: g' = g ^ ((row>>1)&3).
  const int off0 = tid * 16;
  const int row0 = off0 >> 6;
  const int gs   = (off0 >> 4) & 3;                     // linear granule
  const int ce0  = (gs ^ ((row0 >> 1) & 3)) * 8;        // swizzled source offset
  const short* gA0 = xb  + (size_t)(brow + row0) * NDIM + ce0;
  const short* gA1 = xb  + (size_t)(brow + row0 + 128) * NDIM + ce0;
  const short* gB0 = w1t + (size_t)(bcol + row0) * NDIM + ce0;
  const short* gB1 = w1t + (size_t)(bcol + row0 + 128) * NDIM + ce0;

#define GLOAD(src, dst) __builtin_amdgcn_global_load_lds( \
    (const __attribute__((address_space(1))) void*)(src), \
    (__attribute__((address_space(3))) void*)(dst), 16, 0, 0)

#define STAGE_HALF(buf, tile_, kh) do { \
    char* bA_ = smem + (buf) * 32768 + (kh) * 16384; \
    char* bB_ = smem + 65536 + (buf) * 32768 + (kh) * 16384; \
    int ks_ = (tile_) * 64 + (kh) * 32; \
    GLOAD(gA0 + ks_, bA_ + off0); \
    GLOAD(gA1 + ks_, bA_ + off0 + 8192); \
    GLOAD(gB0 + ks_, bB_ + off0); \
    GLOAD(gB1 + ks_, bB_ + off0 + 8192); \
  } while (0)

#define DS_BFR(buf, kh) do { \
    const short* Bb_ = (const short*)(smem + 65536 + (buf) * 32768 + (kh) * 16384); \
    _Pragma("unroll") \
    for (int ni = 0; ni < 4; ++ni) \
      bfr[ni] = *(const bf16x8*)(Bb_ + (wc * 64 + ni * 16 + fr) * 32 + fko); \
  } while (0)

#define DS_AF(buf, kh, mh) do { \
    const short* Ab_ = (const short*)(smem + (buf) * 32768 + (kh) * 16384); \
    _Pragma("unroll") \
    for (int mi = 0; mi < 4; ++mi) \
      af[mi] = *(const bf16x8*)(Ab_ + (wr * 128 + ((mh) * 4 + mi) * 16 + fr) * 32 + fko); \
  } while (0)

  // swapped operands: acc[mi][ni] = C^T fragment
  // value(lane,reg) = C[row = mi*16+(lane&15)][col = ni*16+(lane>>4)*4+reg]
#define MFMA16(mh) do { \
    __builtin_amdgcn_s_setprio(1); \
    _Pragma("unroll") \
    for (int mi = 0; mi < 4; ++mi) \
      _Pragma("unroll") \
      for (int ni = 0; ni < 4; ++ni) \
        acc[(mh) * 4 + mi][ni] = __builtin_amdgcn_mfma_f32_16x16x32_bf16( \
            bfr[ni], af[mi], acc[(mh) * 4 + mi][ni], 0, 0, 0); \
    __builtin_amdgcn_s_setprio(0); \
  } while (0)

#define BAR() __builtin_amdgcn_s_barrier()
#define LGKM0() asm volatile("s_waitcnt lgkmcnt(0)" ::: "memory")
#define WCNT(s) asm volatile("s_waitcnt " s ::: "memory")

#define ITER(kk, DO_S0, DO_S2, V1, V3) do { \
    int b_ = (kk) & 1; \
    bf16x8 af[4], bfr[4]; \
    if (DO_S0) STAGE_HALF(((kk) + 1) & 1, (kk) + 1, 1); \
    DS_BFR(b_, 0); DS_AF(b_, 0, 0); \
    BAR(); LGKM0(); \
    MFMA16(0); \
    BAR(); \
    DS_AF(b_, 0, 1); \
    BAR(); LGKM0(); \
    MFMA16(1); \
    WCNT(V1); BAR(); \
    if (DO_S2) STAGE_HALF(b_, (kk) + 2, 0); \
    DS_BFR(b_, 1); DS_AF(b_, 1, 0); \
    BAR(); LGKM0(); \
    MFMA16(0); \
    BAR(); \
    DS_AF(b_, 1, 1); \
    BAR(); LGKM0(); \
    MFMA16(1); \
    WCNT(V3); BAR(); \
  } while (0)

  // prologue: kh0(0), kh1(0), kh0(1) in flight (12); retire kh0(0)
  STAGE_HALF(0, 0, 0);
  STAGE_HALF(0, 0, 1);
  STAGE_HALF(1, 1, 0);
  WCNT("vmcnt(8)");
  BAR();

  #pragma unroll 1
  for (int kt = 0; kt < 6; ++kt)
    ITER(kt, true, true, "vmcnt(8)", "vmcnt(8)");
  ITER(6, true, false, "vmcnt(8)", "vmcnt(4)");
  ITER(7, false, false, "vmcnt(0)", "vmcnt(0)");

  // ---- epilogue: bias + relu + csum; padded-LDS repack -> coalesced stores
  const int cr = lane & 15;            // output row within 16-frag
  const int cg = (lane >> 4) * 4;      // output col base within 16-frag
  float4 bias4[4];
  #pragma unroll
  for (int ni = 0; ni < 4; ++ni)
    bias4[ni] = *(const float4*)(b1 + bcol + wc * 64 + ni * 16 + cg);

  float cl[4][4];
  #pragma unroll
  for (int ni = 0; ni < 4; ++ni)
    #pragma unroll
    for (int r = 0; r < 4; ++r)
      cl[ni][r] = 0.f;

  short* pk = (short*)smem;            // [128][264] shorts = 67584 B (fits 128 KB)
  #pragma unroll 1
  for (int half = 0; half < 2; ++half) {
    __syncthreads();                   // K-loop reads / prev half's stores done
    if (wr == half) {                  // owning waves write their 128 rows
      #pragma unroll
      for (int mi = 0; mi < 8; ++mi) {
        int lrow = mi * 16 + cr;       // 0..127 within half
        #pragma unroll
        for (int ni = 0; ni < 4; ++ni) {
          float v0 = fmaxf(acc[mi][ni][0] + bias4[ni].x, 0.f);
          float v1 = fmaxf(acc[mi][ni][1] + bias4[ni].y, 0.f);
          float v2 = fmaxf(acc[mi][ni][2] + bias4[ni].z, 0.f);
          float v3 = fmaxf(acc[mi][ni][3] + bias4[ni].w, 0.f);
          cl[ni][0] += v0; cl[ni][1] += v1; cl[ni][2] += v2; cl[ni][3] += v3;
          short4 o;
          o.x = f2b(v0); o.y = f2b(v1); o.z = f2b(v2); o.w = f2b(v3);
          *(short4*)(pk + lrow * 264 + wc * 64 + ni * 16 + cg) = o;
        }
      }
    }
    __syncthreads();
    // all 8 waves store 64 KB: 128 rows x 512 B, fully coalesced b128
    #pragma unroll
    for (int i = 0; i < 8; ++i) {
      int c = tid + i * 512;           // 0..4095 chunks of 16 B
      int row = c >> 5, ch = c & 31;
      bf16x8 vv = *(const bf16x8*)(pk + row * 264 + ch * 8);
      *(bf16x8*)(Aout + (size_t)(brow + half * 128 + row) * HID + bcol + ch * 8) = vv;
    }
  }

  // column sums: reduce over the 16 rows (lanes sharing lane>>4)
  #pragma unroll
  for (int ni = 0; ni < 4; ++ni)
    #pragma unroll
    for (int r = 0; r < 4; ++r) {
      #pragma unroll
      for (int m = 1; m < 16; m <<= 1)
        cl[ni][r] += __shfl_xor(cl[ni][r], m);
    }
  if (cr == 0) {                       // 4 lanes/wave; wr=0/1 -> 2-way contention
    #pragma unroll
    for (int ni = 0; ni < 4; ++ni)
      #pragma unroll
      for (int r = 0; r < 4; ++r)
        atomicAdd(&csum[wc * 64 + ni * 16 + cg + r], cl[ni][r]);
  }
  __syncthreads();
  if (tid < 256) atomicAdd(&colsum[bcol + tid], csum[tid]);
}

// ---- K2: vout[col] += sum_i vin[i] * W[i][col]  (W: [4096][4096] fp32) ----
__global__ __launch_bounds__(256) void k_gemv_at(const float* __restrict__ W,
                                                 const float* __restrict__ vin,
                                                 float* __restrict__ vout) {
  const int col = blockIdx.x * 1024 + threadIdx.x * 4;
  const int r0  = blockIdx.y * 64;
  float4 accv = {0.f, 0.f, 0.f, 0.f};
  const float* base = W + (size_t)r0 * HID + col;
  #pragma unroll 16
  for (int i = 0; i < 64; ++i) {
    float vi = vin[r0 + i];
    float4 wv = *(const float4*)(base + (size_t)i * HID);
    accv.x += vi * wv.x; accv.y += vi * wv.y;
    accv.z += vi * wv.z; accv.w += vi * wv.w;
  }
  atomicAdd(&vout[col + 0], accv.x);
  atomicAdd(&vout[col + 1], accv.y);
  atomicAdd(&vout[col + 2], accv.z);
  atomicAdd(&vout[col + 3], accv.w);
}

// ---- K3: t[row] = W2[row,:] . s ; extra block computes beta = b2 . s ----
__global__ __launch_bounds__(256) void k_gemv_row(const float* __restrict__ W,
                                                  const float* __restrict__ vin,
                                                  const float* __restrict__ b2,
                                                  float* __restrict__ vout,
                                                  float* __restrict__ beta) {
  __shared__ float red[4];
  if (blockIdx.x == HID / 4) {           // beta block
    float p = 0.f;
    for (int j = threadIdx.x; j < HID; j += 256) p += b2[j] * vin[j];
    #pragma unroll
    for (int o = 32; o > 0; o >>= 1) p += __shfl_down(p, o);
    int lane = threadIdx.x & 63, w = threadIdx.x >> 6;
    if (lane == 0) red[w] = p;
    __syncthreads();
    if (threadIdx.x == 0) beta[0] = red[0] + red[1] + red[2] + red[3];
    return;
  }
  int w = threadIdx.x >> 6, lane = threadIdx.x & 63;
  int row = blockIdx.x * 4 + w;
  const float* base = W + (size_t)row * HID;
  float p = 0.f;
  #pragma unroll 8
  for (int j = lane * 4; j < HID; j += 256) {
    float4 wv = *(const float4*)(base + j);
    float4 sv = *(const float4*)(vin + j);
    p += wv.x * sv.x + wv.y * sv.y + wv.z * sv.z + wv.w * sv.w;
  }
  #pragma unroll
  for (int o = 32; o > 0; o >>= 1) p += __shfl_down(p, o);
  if (lane == 0) vout[row] = p;
}

// ---- K4: kv[row] = A[row,:] . t + beta   (A bf16) ----
__global__ __launch_bounds__(256) void k_kv(const short* __restrict__ A,
                                            const float* __restrict__ t,
                                            const float* __restrict__ beta,
                                            float* __restrict__ kv) {
  int w = threadIdx.x >> 6, lane = threadIdx.x & 63;
  int row = blockIdx.x * 4 + w;
  const short* base = A + (size_t)row * HID;
  float p = 0.f;
  #pragma unroll
  for (int j = lane * 8; j < HID; j += 512) {
    bf16x8 av = *(const bf16x8*)(base + j);
    float4 t0 = *(const float4*)(t + j);
    float4 t1 = *(const float4*)(t + j + 4);
    p += b2f(av[0]) * t0.x + b2f(av[1]) * t0.y + b2f(av[2]) * t0.z + b2f(av[3]) * t0.w
       + b2f(av[4]) * t1.x + b2f(av[5]) * t1.y + b2f(av[6]) * t1.z + b2f(av[7]) * t1.w;
  }
  #pragma unroll
  for (int o = 32; o > 0; o >>= 1) p += __shfl_down(p, o);
  if (lane == 0) kv[row] = p + beta[0];
}

// ---- K5: fused W3 pass + final: out += sum_c relu(b3[c] + sum_r kv[r]W3[r][c]) W4[c]
// 128 blocks x 512 threads; block owns 32 complete columns (16 row-groups x 256).
// 32 cols x fp32 = 128-B contiguous segment per row per block (HBM burst sweet spot).
__global__ __launch_bounds__(512) void k_w3_final(const float* __restrict__ W3,
                                                  const float* __restrict__ kvv,
                                                  const float* __restrict__ b3,
                                                  const float* __restrict__ W4,
                                                  float* __restrict__ out) {
  __shared__ float part[512];
  const int t  = threadIdx.x;
  const int cl = t & 31;                 // col within block
  const int rg = t >> 5;                 // row-group 0..15
  const int c  = blockIdx.x * 32 + cl;
  const float* base = W3 + (size_t)rg * 256 * HID + c;
  const float* kb   = kvv + rg * 256;
  float p = 0.f;
  #pragma unroll 32
  for (int i = 0; i < 256; ++i)
    p += kb[i] * base[(size_t)i * HID];
  part[t] = p;
  __syncthreads();
  if (t < 32) {
    float u = b3[c];
    #pragma unroll
    for (int g = 0; g < 16; ++g) u += part[g * 32 + t];
    u = fmaxf(u, 0.f);
    float v = u * W4[c];
    #pragma unroll
    for (int o = 16; o > 0; o >>= 1) v += __shfl_down(v, o);
    if (t == 0) atomicAdd(out, v);
  }
}

extern "C" void kernel_launch(void* const* d_in, const int* in_sizes, int n_in,
                              void* d_out, int out_size, void* d_ws, size_t ws_size,
                              hipStream_t stream) {
  const float* x  = (const float*)d_in[0];
  // d_in[1] = edge_index (dead in the reference)
  const float* W1 = (const float*)d_in[2];
  const float* b1 = (const float*)d_in[3];
  const float* W2 = (const float*)d_in[4];
  const float* b2 = (const float*)d_in[5];
  const float* W3 = (const float*)d_in[6];
  const float* b3 = (const float*)d_in[7];
  const float* W4 = (const float*)d_in[8];
  const float* b4 = (const float*)d_in[9];
  float* out = (float*)d_out;

  char* ws = (char*)d_ws;
  short* Abf  = (short*)(ws);                 // 32 MB
  short* xb   = (short*)(ws + 33554432);      // 4 MB
  short* w1t  = (short*)(ws + 37748736);      // 4 MB
  float* aacc = (float*)(ws + 41943040);
  float* svec = (float*)(ws + 41959424);
  float* tvec = (float*)(ws + 41975808);
  float* kvv  = (float*)(ws + 41992192);
  float* beta = (float*)(ws + 42024960);

  k_prep    <<<dim3(3088),     dim3(256), 0, stream>>>(x, W1, b2, b4, xb, w1t, aacc, svec, out);
  k_gemm1   <<<dim3(256),      dim3(512), 131072, stream>>>(xb, w1t, b1, Abf, aacc);
  k_gemv_at <<<dim3(4, 64),    dim3(256), 0, stream>>>(W2, aacc, svec);
  k_gemv_row<<<dim3(1025),     dim3(256), 0, stream>>>(W2, svec, b2, tvec, beta);
  k_kv      <<<dim3(1024),     dim3(256), 0, stream>>>(Abf, tvec, beta, kvv);
  k_w3_final<<<dim3(128),      dim3(512), 0, stream>>>(W3, kvv, b3, W4, out);
}

// Round 19
// 86.324 us; speedup vs baseline: 1.0861x; 1.0011x over previous
//
#include <hip/hip_runtime.h>

#define NODES 4096
#define NDIM  512
#define HID   4096

typedef __attribute__((ext_vector_type(8))) short bf16x8;
typedef __attribute__((ext_vector_type(4))) float f32x4;

__device__ __forceinline__ float b2f(short v) {
  union { unsigned int u; float f; } c;
  c.u = ((unsigned int)(unsigned short)v) << 16;
  return c.f;
}
__device__ __forceinline__ short f2b(float f) {
  union { float f; unsigned int u; } c; c.f = f;
  unsigned int r = c.u + 0x7fffu + ((c.u >> 16) & 1u);  // round-nearest-even
  return (short)(r >> 16);
}

// ---- K0: fused prep: cast x->bf16 (16B stores) | transpose W1 | init accs ----
__global__ __launch_bounds__(256) void k_prep(const float* __restrict__ x,
                                              const float* __restrict__ W1,
                                              const float* __restrict__ b2,
                                              const float* __restrict__ b4,
                                              short* __restrict__ xb,
                                              short* __restrict__ w1t,
                                              float* __restrict__ aacc,
                                              float* __restrict__ svec,
                                              float* __restrict__ out) {
  __shared__ float tile[32][33];
  int b = blockIdx.x;
  if (b < 1024) {                       // cast x (4096x512 fp32 -> bf16), 8/thread
    int i = (b * 256 + threadIdx.x) * 8;
    float4 v0 = *(const float4*)(x + i);
    float4 v1 = *(const float4*)(x + i + 4);
    bf16x8 o;
    o[0] = f2b(v0.x); o[1] = f2b(v0.y); o[2] = f2b(v0.z); o[3] = f2b(v0.w);
    o[4] = f2b(v1.x); o[5] = f2b(v1.y); o[6] = f2b(v1.z); o[7] = f2b(v1.w);
    *(bf16x8*)(xb + i) = o;
  } else if (b < 3072) {                // transpose W1 [512][4096] -> [4096][512] bf16
    int t = b - 1024;
    int n0 = (t & 127) * 32;
    int k0 = (t >> 7) * 32;
    int tx = threadIdx.x & 31, ty = threadIdx.x >> 5;
    #pragma unroll
    for (int j = 0; j < 4; ++j) {
      int kk = ty + j * 8;
      tile[kk][tx] = W1[(size_t)(k0 + kk) * HID + n0 + tx];
    }
    __syncthreads();
    #pragma unroll
    for (int j = 0; j < 4; ++j) {
      int nn = ty + j * 8;
      w1t[(size_t)(n0 + nn) * NDIM + k0 + tx] = f2b(tile[tx][nn]);
    }
  } else {                              // init: a=0, s=N*b2, out=b4
    int j = (b - 3072) * 256 + threadIdx.x;
    aacc[j] = 0.0f;
    svec[j] = (float)NODES * b2[j];
    if (b == 3072 && threadIdx.x == 0) out[0] = b4[0];
  }
}

// ---- K1: A = relu(x @ W1 + b1) (bf16 MFMA), fused column sums ----
// 256x256 tile, BK=64, 8 waves (2M x 4N, 128x64/wave). 2-phase-per-K-tile
// fine interleave (merged mh): {stage half-tile || 12 ds_read -> barrier ->
// lgkmcnt(0) -> 32 MFMA -> counted vmcnt -> barrier} x2. Same vmcnt ledger
// as the proven 4-phase R12 schedule; half the barriers (4/K-tile vs 8).
__global__ __launch_bounds__(512, 2) void k_gemm1(const short* __restrict__ xb,
                                                  const short* __restrict__ w1t,
                                                  const float* __restrict__ b1,
                                                  short* __restrict__ Aout,
                                                  float* __restrict__ colsum) {
  extern __shared__ char smem[];        // 131072 B:
                                        // A: buf*32768 + kh*16384   (0..65535)
                                        // B: 65536 + buf*32768 + kh*16384
  __shared__ float csum[256];

  const int tid  = threadIdx.x;
  const int lane = tid & 63;
  const int wid  = tid >> 6;            // 0..7
  const int wr   = wid >> 2;            // 0..1  (M)
  const int wc   = wid & 3;             // 0..3  (N)

  // XCD-aware swizzle (256 blocks, %8==0 -> simple bijective form)
  int bswz = (blockIdx.x & 7) * 32 + (blockIdx.x >> 3);
  const int brow = (bswz >> 4) * 256, bcol = (bswz & 15) * 256;

  f32x4 acc[8][4];
  #pragma unroll
  for (int i = 0; i < 8; ++i)
    #pragma unroll
    for (int j = 0; j < 4; ++j)
      acc[i][j] = (f32x4){0.f, 0.f, 0.f, 0.f};

  if (tid < 256) csum[tid] = 0.f;

  const int fr = lane & 15;
  // swizzled fragment granule: logical g = lane>>4, row-phase = (fr>>1)&3
  const int fko = ((lane >> 4) ^ ((lane >> 1) & 3)) * 8;  // shorts, in [0,32)

  // staging: each kh-subtile is [256][32] shorts (64-B rows), LDS dest linear.
  // Source granule pre-swizzled with the SAME involution: g' = g ^ ((row>>1)&3).
  const int off0 = tid * 16;
  const int row0 = off0 >> 6;
  const int gs   = (off0 >> 4) & 3;                     // linear granule
  const int ce0  = (gs ^ ((row0 >> 1) & 3)) * 8;        // swizzled source offset
  const short* gA0 = xb  + (size_t)(brow + row0) * NDIM + ce0;
  const short* gA1 = xb  + (size_t)(brow + row0 + 128) * NDIM + ce0;
  const short* gB0 = w1t + (size_t)(bcol + row0) * NDIM + ce0;
  const short* gB1 = w1t + (size_t)(bcol + row0 + 128) * NDIM + ce0;

#define GLOAD(src, dst) __builtin_amdgcn_global_load_lds( \
    (const __attribute__((address_space(1))) void*)(src), \
    (__attribute__((address_space(3))) void*)(dst), 16, 0, 0)

#define STAGE_HALF(buf, tile_, kh) do { \
    char* bA_ = smem + (buf) * 32768 + (kh) * 16384; \
    char* bB_ = smem + 65536 + (buf) * 32768 + (kh) * 16384; \
    int ks_ = (tile_) * 64 + (kh) * 32; \
    GLOAD(gA0 + ks_, bA_ + off0); \
    GLOAD(gA1 + ks_, bA_ + off0 + 8192); \
    GLOAD(gB0 + ks_, bB_ + off0); \
    GLOAD(gB1 + ks_, bB_ + off0 + 8192); \
  } while (0)

#define DS_BFR(buf, kh) do { \
    const short* Bb_ = (const short*)(smem + 65536 + (buf) * 32768 + (kh) * 16384); \
    _Pragma("unroll") \
    for (int ni = 0; ni < 4; ++ni) \
      bfr[ni] = *(const bf16x8*)(Bb_ + (wc * 64 + ni * 16 + fr) * 32 + fko); \
  } while (0)

#define DS_AF8(buf, kh) do { \
    const short* Ab_ = (const short*)(smem + (buf) * 32768 + (kh) * 16384); \
    _Pragma("unroll") \
    for (int mi = 0; mi < 8; ++mi) \
      af[mi] = *(const bf16x8*)(Ab_ + (wr * 128 + mi * 16 + fr) * 32 + fko); \
  } while (0)

  // swapped operands: acc[mi][ni] = C^T fragment
  // value(lane,reg) = C[row = mi*16+(lane&15)][col = ni*16+(lane>>4)*4+reg]
#define MFMA32() do { \
    __builtin_amdgcn_s_setprio(1); \
    _Pragma("unroll") \
    for (int mi = 0; mi < 8; ++mi) \
      _Pragma("unroll") \
      for (int ni = 0; ni < 4; ++ni) \
        acc[mi][ni] = __builtin_amdgcn_mfma_f32_16x16x32_bf16( \
            bfr[ni], af[mi], acc[mi][ni], 0, 0, 0); \
    __builtin_amdgcn_s_setprio(0); \
  } while (0)

#define BAR() __builtin_amdgcn_s_barrier()
#define LGKM0() asm volatile("s_waitcnt lgkmcnt(0)" ::: "memory")
#define WCNT(s) asm volatile("s_waitcnt " s ::: "memory")

  // One K-tile = 2 phases. Stage positions and vmcnt constants identical to
  // the proven 4-phase schedule: ph0 stages kh1(k+1), waits V1 (covers kh1(k));
  // ph1 stages kh0(k+2), waits V3 (covers kh0(k+1)).
#define ITER(kk, DO_S0, DO_S2, V1, V3) do { \
    int b_ = (kk) & 1; \
    bf16x8 af[8], bfr[4]; \
    /* ph0: kh0, all 8 mi */ \
    if (DO_S0) STAGE_HALF(((kk) + 1) & 1, (kk) + 1, 1); \
    DS_BFR(b_, 0); DS_AF8(b_, 0); \
    BAR(); LGKM0(); \
    MFMA32(); \
    WCNT(V1); BAR(); \
    /* ph1: kh1, all 8 mi */ \
    if (DO_S2) STAGE_HALF(b_, (kk) + 2, 0); \
    DS_BFR(b_, 1); DS_AF8(b_, 1); \
    BAR(); LGKM0(); \
    MFMA32(); \
    WCNT(V3); BAR(); \
  } while (0)

  // prologue: kh0(0), kh1(0), kh0(1) in flight (12); retire kh0(0)
  STAGE_HALF(0, 0, 0);
  STAGE_HALF(0, 0, 1);
  STAGE_HALF(1, 1, 0);
  WCNT("vmcnt(8)");
  BAR();

  #pragma unroll 1
  for (int kt = 0; kt < 6; ++kt)
    ITER(kt, true, true, "vmcnt(8)", "vmcnt(8)");
  ITER(6, true, false, "vmcnt(8)", "vmcnt(4)");
  ITER(7, false, false, "vmcnt(0)", "vmcnt(0)");

  // ---- epilogue: bias + relu + csum; padded-LDS repack -> coalesced stores
  const int cr = lane & 15;            // output row within 16-frag
  const int cg = (lane >> 4) * 4;      // output col base within 16-frag
  float4 bias4[4];
  #pragma unroll
  for (int ni = 0; ni < 4; ++ni)
    bias4[ni] = *(const float4*)(b1 + bcol + wc * 64 + ni * 16 + cg);

  float cl[4][4];
  #pragma unroll
  for (int ni = 0; ni < 4; ++ni)
    #pragma unroll
    for (int r = 0; r < 4; ++r)
      cl[ni][r] = 0.f;

  short* pk = (short*)smem;            // [128][264] shorts = 67584 B (fits 128 KB)
  #pragma unroll 1
  for (int half = 0; half < 2; ++half) {
    __syncthreads();                   // K-loop reads / prev half's stores done
    if (wr == half) {                  // owning waves write their 128 rows
      #pragma unroll
      for (int mi = 0; mi < 8; ++mi) {
        int lrow = mi * 16 + cr;       // 0..127 within half
        #pragma unroll
        for (int ni = 0; ni < 4; ++ni) {
          float v0 = fmaxf(acc[mi][ni][0] + bias4[ni].x, 0.f);
          float v1 = fmaxf(acc[mi][ni][1] + bias4[ni].y, 0.f);
          float v2 = fmaxf(acc[mi][ni][2] + bias4[ni].z, 0.f);
          float v3 = fmaxf(acc[mi][ni][3] + bias4[ni].w, 0.f);
          cl[ni][0] += v0; cl[ni][1] += v1; cl[ni][2] += v2; cl[ni][3] += v3;
          short4 o;
          o.x = f2b(v0); o.y = f2b(v1); o.z = f2b(v2); o.w = f2b(v3);
          *(short4*)(pk + lrow * 264 + wc * 64 + ni * 16 + cg) = o;
        }
      }
    }
    __syncthreads();
    // all 8 waves store 64 KB: 128 rows x 512 B, fully coalesced b128
    #pragma unroll
    for (int i = 0; i < 8; ++i) {
      int c = tid + i * 512;           // 0..4095 chunks of 16 B
      int row = c >> 5, ch = c & 31;
      bf16x8 vv = *(const bf16x8*)(pk + row * 264 + ch * 8);
      *(bf16x8*)(Aout + (size_t)(brow + half * 128 + row) * HID + bcol + ch * 8) = vv;
    }
  }

  // column sums: reduce over the 16 rows (lanes sharing lane>>4)
  #pragma unroll
  for (int ni = 0; ni < 4; ++ni)
    #pragma unroll
    for (int r = 0; r < 4; ++r) {
      #pragma unroll
      for (int m = 1; m < 16; m <<= 1)
        cl[ni][r] += __shfl_xor(cl[ni][r], m);
    }
  if (cr == 0) {                       // 4 lanes/wave; wr=0/1 -> 2-way contention
    #pragma unroll
    for (int ni = 0; ni < 4; ++ni)
      #pragma unroll
      for (int r = 0; r < 4; ++r)
        atomicAdd(&csum[wc * 64 + ni * 16 + cg + r], cl[ni][r]);
  }
  __syncthreads();
  if (tid < 256) atomicAdd(&colsum[bcol + tid], csum[tid]);
}

// ---- K2: vout[col] += sum_i vin[i] * W[i][col]  (W: [4096][4096] fp32) ----
__global__ __launch_bounds__(256) void k_gemv_at(const float* __restrict__ W,
                                                 const float* __restrict__ vin,
                                                 float* __restrict__ vout) {
  const int col = blockIdx.x * 1024 + threadIdx.x * 4;
  const int r0  = blockIdx.y * 64;
  float4 accv = {0.f, 0.f, 0.f, 0.f};
  const float* base = W + (size_t)r0 * HID + col;
  #pragma unroll 16
  for (int i = 0; i < 64; ++i) {
    float vi = vin[r0 + i];
    float4 wv = *(const float4*)(base + (size_t)i * HID);
    accv.x += vi * wv.x; accv.y += vi * wv.y;
    accv.z += vi * wv.z; accv.w += vi * wv.w;
  }
  atomicAdd(&vout[col + 0], accv.x);
  atomicAdd(&vout[col + 1], accv.y);
  atomicAdd(&vout[col + 2], accv.z);
  atomicAdd(&vout[col + 3], accv.w);
}

// ---- K3: t[row] = W2[row,:] . s ; extra block computes beta = b2 . s ----
__global__ __launch_bounds__(256) void k_gemv_row(const float* __restrict__ W,
                                                  const float* __restrict__ vin,
                                                  const float* __restrict__ b2,
                                                  float* __restrict__ vout,
                                                  float* __restrict__ beta) {
  __shared__ float red[4];
  if (blockIdx.x == HID / 4) {           // beta block
    float p = 0.f;
    for (int j = threadIdx.x; j < HID; j += 256) p += b2[j] * vin[j];
    #pragma unroll
    for (int o = 32; o > 0; o >>= 1) p += __shfl_down(p, o);
    int lane = threadIdx.x & 63, w = threadIdx.x >> 6;
    if (lane == 0) red[w] = p;
    __syncthreads();
    if (threadIdx.x == 0) beta[0] = red[0] + red[1] + red[2] + red[3];
    return;
  }
  int w = threadIdx.x >> 6, lane = threadIdx.x & 63;
  int row = blockIdx.x * 4 + w;
  const float* base = W + (size_t)row * HID;
  float p = 0.f;
  #pragma unroll 8
  for (int j = lane * 4; j < HID; j += 256) {
    float4 wv = *(const float4*)(base + j);
    float4 sv = *(const float4*)(vin + j);
    p += wv.x * sv.x + wv.y * sv.y + wv.z * sv.z + wv.w * sv.w;
  }
  #pragma unroll
  for (int o = 32; o > 0; o >>= 1) p += __shfl_down(p, o);
  if (lane == 0) vout[row] = p;
}

// ---- K4: kv[row] = A[row,:] . t + beta   (A bf16) ----
__global__ __launch_bounds__(256) void k_kv(const short* __restrict__ A,
                                            const float* __restrict__ t,
                                            const float* __restrict__ beta,
                                            float* __restrict__ kv) {
  int w = threadIdx.x >> 6, lane = threadIdx.x & 63;
  int row = blockIdx.x * 4 + w;
  const short* base = A + (size_t)row * HID;
  float p = 0.f;
  #pragma unroll
  for (int j = lane * 8; j < HID; j += 512) {
    bf16x8 av = *(const bf16x8*)(base + j);
    float4 t0 = *(const float4*)(t + j);
    float4 t1 = *(const float4*)(t + j + 4);
    p += b2f(av[0]) * t0.x + b2f(av[1]) * t0.y + b2f(av[2]) * t0.z + b2f(av[3]) * t0.w
       + b2f(av[4]) * t1.x + b2f(av[5]) * t1.y + b2f(av[6]) * t1.z + b2f(av[7]) * t1.w;
  }
  #pragma unroll
  for (int o = 32; o > 0; o >>= 1) p += __shfl_down(p, o);
  if (lane == 0) kv[row] = p + beta[0];
}

// ---- K5: fused W3 pass + final: out += sum_c relu(b3[c] + sum_r kv[r]W3[r][c]) W4[c]
// 128 blocks x 512 threads; block owns 32 complete columns (16 row-groups x 256).
// 32 cols x fp32 = 128-B contiguous segment per row per block (HBM burst sweet spot).
__global__ __launch_bounds__(512) void k_w3_final(const float* __restrict__ W3,
                                                  const float* __restrict__ kvv,
                                                  const float* __restrict__ b3,
                                                  const float* __restrict__ W4,
                                                  float* __restrict__ out) {
  __shared__ float part[512];
  const int t  = threadIdx.x;
  const int cl = t & 31;                 // col within block
  const int rg = t >> 5;                 // row-group 0..15
  const int c  = blockIdx.x * 32 + cl;
  const float* base = W3 + (size_t)rg * 256 * HID + c;
  const float* kb   = kvv + rg * 256;
  float p = 0.f;
  #pragma unroll 32
  for (int i = 0; i < 256; ++i)
    p += kb[i] * base[(size_t)i * HID];
  part[t] = p;
  __syncthreads();
  if (t < 32) {
    float u = b3[c];
    #pragma unroll
    for (int g = 0; g < 16; ++g) u += part[g * 32 + t];
    u = fmaxf(u, 0.f);
    float v = u * W4[c];
    #pragma unroll
    for (int o = 16; o > 0; o >>= 1) v += __shfl_down(v, o);
    if (t == 0) atomicAdd(out, v);
  }
}

extern "C" void kernel_launch(void* const* d_in, const int* in_sizes, int n_in,
                              void* d_out, int out_size, void* d_ws, size_t ws_size,
                              hipStream_t stream) {
  const float* x  = (const float*)d_in[0];
  // d_in[1] = edge_index (dead in the reference)
  const float* W1 = (const float*)d_in[2];
  const float* b1 = (const float*)d_in[3];
  const float* W2 = (const float*)d_in[4];
  const float* b2 = (const float*)d_in[5];
  const float* W3 = (const float*)d_in[6];
  const float* b3 = (const float*)d_in[7];
  const float* W4 = (const float*)d_in[8];
  const float* b4 = (const float*)d_in[9];
  float* out = (float*)d_out;

  char* ws = (char*)d_ws;
  short* Abf  = (short*)(ws);                 // 32 MB
  short* xb   = (short*)(ws + 33554432);      // 4 MB
  short* w1t  = (short*)(ws + 37748736);      // 4 MB
  float* aacc = (float*)(ws + 41943040);
  float* svec = (float*)(ws + 41959424);
  float* tvec = (float*)(ws + 41975808);
  float* kvv  = (float*)(ws + 41992192);
  float* beta = (float*)(ws + 42024960);

  k_prep    <<<dim3(3088),     dim3(256), 0, stream>>>(x, W1, b2, b4, xb, w1t, aacc, svec, out);
  k_gemm1   <<<dim3(256),      dim3(512), 131072, stream>>>(xb, w1t, b1, Abf, aacc);
  k_gemv_at <<<dim3(4, 64),    dim3(256), 0, stream>>>(W2, aacc, svec);
  k_gemv_row<<<dim3(1025),     dim3(256), 0, stream>>>(W2, svec, b2, tvec, beta);
  k_kv      <<<dim3(1024),     dim3(256), 0, stream>>>(Abf, tvec, beta, kvv);
  k_w3_final<<<dim3(128),      dim3(512), 0, stream>>>(W3, kvv, b3, W4, out);
}